// Round 17
// baseline (184.548 us; speedup 1.0000x reference)
//
#include <hip/hip_runtime.h>
#include <hip/hip_bf16.h>

// Problem constants
#define BB 2
#define LL 2048
#define DD 1024
#define HH 16
#define FD 16
#define HD 64
#define EPS 1e-5f
#define RQKV 1536   // fused QKV row stride (256 Q + 256 K + 1024 V)
#define NFIX 4      // first NFIX positions per (b,h) recomputed in fp32 (low-z rows)

typedef __attribute__((ext_vector_type(4))) float f32x4;
typedef __attribute__((ext_vector_type(8))) _Float16 f16x8;
typedef __attribute__((ext_vector_type(4))) _Float16 f16x4;

// ---------------------------------------------------------------------------
// prep: fused pre-pass, branch on block range (round-15/16 verified).
//   [0,1536):    transpose+cast [Wq|Wk|Wv] -> WqkvT fp16 [1536][1024]
//   [1536,2560): transpose+cast Wo -> WoT fp16 [1024][1024]
//   [2560,2608): early_qkv — QKVe[8][1536] = hs_early[8][1024] @ W, fp32
//     (early rows must come from fp32 inputs: fp16-sourced q,k give |ds|~4e-4,
//      which s^2/(z+eps) amplifies to ~0.1 output error on low-z rows.)
//   [2608,3632): cast hs fp32 -> HS16 fp16 (shared A operand pre-cast ONCE —
//      round 14 proved folding this into the multi-reuse GEMM doubles HBM).
// ---------------------------------------------------------------------------
__global__ __launch_bounds__(256) void prep(
    const float* __restrict__ Wq, const float* __restrict__ Wk,
    const float* __restrict__ Wv, const float* __restrict__ Wo,
    const float* __restrict__ hs, _Float16* __restrict__ WqkvT,
    _Float16* __restrict__ WoT, float* __restrict__ QKVe,
    _Float16* __restrict__ HS16) {
  __shared__ __attribute__((aligned(16))) char smem[40960];
  const int bx = blockIdx.x;
  const int tid = threadIdx.x;

  if (bx >= 2608) {
    // ---- cast_hs path ----
    int idx = ((bx - 2608) * 256 + tid) * 16;
#pragma unroll
    for (int half = 0; half < 2; half++) {
      float4 a = *(const float4*)(hs + idx + half * 8);
      float4 b = *(const float4*)(hs + idx + half * 8 + 4);
      f16x8 p = {(_Float16)a.x, (_Float16)a.y, (_Float16)a.z, (_Float16)a.w,
                 (_Float16)b.x, (_Float16)b.y, (_Float16)b.z, (_Float16)b.w};
      *(f16x8*)(HS16 + idx + half * 8) = p;
    }
    return;
  }

  if (bx < 2560) {
    // ---- transpose+cast path ----
    _Float16(*s)[40] = (_Float16(*)[40])smem;
    const float* src;
    _Float16* dst;
    int n0, ncol, drow, k0;
    if (bx < 1536) {
      int ct = bx % 48, kt = bx / 48;
      if (ct < 8) { src = Wq; n0 = ct * 32; ncol = 256; drow = n0; }
      else if (ct < 16) { src = Wk; n0 = (ct - 8) * 32; ncol = 256; drow = 256 + n0; }
      else { src = Wv; n0 = (ct - 16) * 32; ncol = 1024; drow = 512 + n0; }
      k0 = kt * 32;
      dst = WqkvT;
    } else {
      int i2 = bx - 1536;
      n0 = (i2 & 31) * 32; k0 = (i2 >> 5) * 32;
      src = Wo; ncol = DD; drow = n0; dst = WoT;
    }
    {
      int r = tid >> 3, c = (tid & 7) * 4;
      float4 v = *(const float4*)(src + (size_t)(k0 + r) * ncol + n0 + c);
      f16x4 p = {(_Float16)v.x, (_Float16)v.y, (_Float16)v.z, (_Float16)v.w};
      *(f16x4*)&s[r][c] = p;
    }
    __syncthreads();
    {
      int n = tid >> 3, kk = (tid & 7) * 4;
      f16x4 o = {s[kk + 0][n], s[kk + 1][n], s[kk + 2][n], s[kk + 3][n]};
      *(f16x4*)(dst + (size_t)(drow + n) * DD + k0 + kk) = o;
    }
    return;
  }

  // ---- early_qkv path ----
  float(*sHS)[DD] = (float(*)[DD])smem;                      // 32 KB
  float(*part)[8][32] = (float(*)[8][32])(smem + 32768);     // 8 KB
  const int kg = tid >> 5, c = tid & 31;
  const int c0 = (bx - 2560) * 32;

  for (int i = tid; i < 8 * (DD / 4); i += 256) {
    int e = i / (DD / 4), col4 = (i % (DD / 4)) * 4;
    int b = e >> 2, r = e & 3;
    *(float4*)&sHS[e][col4] =
        *(const float4*)(hs + (size_t)(b * LL + r) * DD + col4);
  }
  __syncthreads();

  const float* W;
  int col, ncol;
  if (c0 < 256) { W = Wq; col = c0 + c; ncol = 256; }
  else if (c0 < 512) { W = Wk; col = (c0 - 256) + c; ncol = 256; }
  else { W = Wv; col = (c0 - 512) + c; ncol = 1024; }

  float acc[8] = {};
  const int d0 = kg * 128;
#pragma unroll 4
  for (int d = d0; d < d0 + 128; d++) {
    float wv = W[(size_t)d * ncol + col];
#pragma unroll
    for (int e = 0; e < 8; e++) acc[e] += sHS[e][d] * wv;
  }
#pragma unroll
  for (int e = 0; e < 8; e++) part[kg][e][c] = acc[e];
  __syncthreads();

  {
    int e = tid >> 5;
    float t = 0.f;
#pragma unroll
    for (int g = 0; g < 8; g++) t += part[g][e][c];
    QKVe[(size_t)e * RQKV + c0 + c] = t;
  }
}

// ---------------------------------------------------------------------------
// fp16 MFMA GEMM, 64x64 tile (round-17): C[M,N] = A[M,K] @ Bt[N,K]^T.
// Rationale: round-14 counters showed the 128x64 version latency-bound with
// both pipes idle at 3 blocks/CU; 64x64 doubles the grid (6/CU QKV, 4/CU
// out-proj) for inter-block latency overlap — the lever rounds 12/13 proved
// decisive at this size. BK=64, 4 waves (2x2, wave tile 32x32), register
// prefetch of the next 64-K slab. XOR-swizzled LDS (no pad): elem (row,k) at
// row*64 + ((k>>3 ^ (row&7))*8 + (k&7)) — staging writes 4-way, fragment
// b128 reads 2-way (free). LDS 16 KB/block.
// Staging: threads <128 stage A (2/row, 32 elems), >=128 stage B.
// ---------------------------------------------------------------------------
template <typename OutT>
__global__ __launch_bounds__(256) void gemm_f16(
    const _Float16* __restrict__ A, const _Float16* __restrict__ Bt,
    OutT* __restrict__ C, int M, int N, int K) {
  __shared__ __attribute__((aligned(16))) _Float16 sA[64 * 64];  // 8 KB
  __shared__ __attribute__((aligned(16))) _Float16 sB[64 * 64];  // 8 KB
  const int tid = threadIdx.x;
  const int m0 = blockIdx.y * 64, n0 = blockIdx.x * 64;
  const int w = tid >> 6, lane = tid & 63, quad = lane >> 4, l16 = lane & 15;
  const int wm = (w >> 1) * 32, wn = (w & 1) * 32;

  // staging: tid<128 -> A row (tid>>1), half tid&1; tid>=128 -> B row, half
  const bool isA = tid < 128;
  const int srow = (tid & 127) >> 1, p = tid & 1;
  const _Float16* Gp = (isA ? A + (size_t)(m0 + srow) * K
                            : Bt + (size_t)(n0 + srow) * K) + p * 32;
  _Float16* sW = (isA ? sA : sB) + srow * 64;
  const int swz = srow & 7;

  f32x4 acc[2][2];
#pragma unroll
  for (int i = 0; i < 2; i++)
#pragma unroll
    for (int j = 0; j < 2; j++) acc[i][j] = (f32x4){0.f, 0.f, 0.f, 0.f};

  f16x8 r[4];
  auto LOAD = [&](int k0) {
#pragma unroll
    for (int i = 0; i < 4; i++) r[i] = *(const f16x8*)(Gp + k0 + i * 8);
  };
  LOAD(0);

  for (int k0 = 0; k0 < K; k0 += 64) {
    __syncthreads();
#pragma unroll
    for (int i = 0; i < 4; i++)
      *(f16x8*)(sW + (((4 * p + i) ^ swz) * 8)) = r[i];
    __syncthreads();
    if (k0 + 64 < K) LOAD(k0 + 64);  // prefetch overlaps the MFMAs below

#pragma unroll
    for (int s = 0; s < 2; s++) {
      f16x8 af[2], bf[2];
#pragma unroll
      for (int i = 0; i < 2; i++) {
        int row = wm + i * 16 + l16;
        int col = ((s * 4 + quad) ^ (row & 7)) * 8;
        af[i] = *(const f16x8*)&sA[row * 64 + col];
      }
#pragma unroll
      for (int j = 0; j < 2; j++) {
        int row = wn + j * 16 + l16;
        int col = ((s * 4 + quad) ^ (row & 7)) * 8;
        bf[j] = *(const f16x8*)&sB[row * 64 + col];
      }
#pragma unroll
      for (int i = 0; i < 2; i++)
#pragma unroll
        for (int j = 0; j < 2; j++)
          acc[i][j] = __builtin_amdgcn_mfma_f32_16x16x32_f16(af[i], bf[j], acc[i][j], 0, 0, 0);
    }
  }

#pragma unroll
  for (int i = 0; i < 2; i++)
#pragma unroll
    for (int j = 0; j < 2; j++)
#pragma unroll
      for (int r2 = 0; r2 < 4; r2++) {
        const int row = m0 + wm + i * 16 + quad * 4 + r2;
        const int col = n0 + wn + j * 16 + l16;
        C[(size_t)row * N + col] = (OutT)acc[i][j][r2];
      }
}

// ---------------------------------------------------------------------------
// MFMA causal quadratic attention, v4 (round-13/16 verified, byte-identical):
// paired complementary query tiles. Block x = i (0..15) handles q-tiles A=i,
// B=31-i: every block does exactly 33 compute-units -> 512 perfectly balanced
// blocks (2/CU). Round 15 measured that adding a 17th grid column for the
// early-row fix slowed this kernel 24% — keep the grid at exactly (16,32).
// Stored S2 = 2*(q.k)^2; o = num/(z + 32*EPS). z via MFMA against ones-row
// tile (sVt rows 64..79). Register prefetch of next K/V tile. Strides 88.
// ---------------------------------------------------------------------------
#define SK4 24
#define SV4 88
#define SS4 88

__global__ __launch_bounds__(256) void attn_mfma4(
    const _Float16* __restrict__ QKV, _Float16* __restrict__ O) {
  __shared__ __attribute__((aligned(16))) _Float16 sK[64 * SK4];
  __shared__ __attribute__((aligned(16))) _Float16 sVt[80 * SV4];
  __shared__ __attribute__((aligned(16))) _Float16 sS2[4 * 32 * SS4];

  const int bh = blockIdx.y;
  const int b = bh >> 4, h = bh & 15;
  const int qtA = blockIdx.x;
  const int qtB = 31 - qtA;
  const int tid = threadIdx.x;
  const int w = tid >> 6;
  const int lane = tid & 63;
  const int quad = lane >> 4;
  const int l16 = lane & 15;
  const int gqA = qtA * 64 + w * 16;
  const int gqB = qtB * 64 + w * 16;

  f16x8 qfragA = {}, qfragB = {};
  if (quad < 2) {
    qfragA = *(const f16x8*)(QKV +
        (size_t)(b * LL + gqA + l16) * RQKV + h * FD + quad * 8);
    qfragB = *(const f16x8*)(QKV +
        (size_t)(b * LL + gqB + l16) * RQKV + h * FD + quad * 8);
  }

  for (int t = tid; t < 16 * SV4; t += 256) {
    int r = t / SV4, c = t % SV4;
    sVt[64 * SV4 + t] = (_Float16)((r == 0 && c < 64) ? 1.0f : 0.0f);
  }
  __syncthreads();
  const f16x8 zf0 = *(const f16x8*)&sVt[(64 + l16) * SV4 + quad * 8];
  const f16x8 zf1 = *(const f16x8*)&sVt[(64 + l16) * SV4 + 32 + quad * 8];

  f32x4 oaccA[4], oaccB[4];
  f32x4 zaccA = (f32x4){0.f, 0.f, 0.f, 0.f};
  f32x4 zaccB = (f32x4){0.f, 0.f, 0.f, 0.f};
#pragma unroll
  for (int nt = 0; nt < 4; nt++) {
    oaccA[nt] = (f32x4){0.f, 0.f, 0.f, 0.f};
    oaccB[nt] = (f32x4){0.f, 0.f, 0.f, 0.f};
  }

  _Float16* sS2B = sS2 + w * 32 * SS4;
  _Float16* sS2A = sS2B + 16 * SS4;

  const int ktiles = qtB + 1;

  const int skey = tid >> 2, sfg = (tid & 3) * 4;
  uint2 kreg;
  f16x8 vreg0, vreg1;
  auto LOAD = [&](int kt) {
    kreg = *(const uint2*)(QKV +
        (size_t)(b * LL + kt * 64 + skey) * RQKV + 256 + h * FD + sfg);
    const _Float16* vp = QKV +
        (size_t)(b * LL + kt * 64 + lane) * RQKV + 512 + h * HD + w * 16;
    vreg0 = *(const f16x8*)vp;
    vreg1 = *(const f16x8*)(vp + 8);
  };
  LOAD(0);

  for (int kt = 0; kt < ktiles; kt++) {
    __syncthreads();
    *(uint2*)&sK[skey * SK4 + sfg] = kreg;
#pragma unroll
    for (int t = 0; t < 8; t++) sVt[(w * 16 + t) * SV4 + lane] = vreg0[t];
#pragma unroll
    for (int t = 0; t < 8; t++) sVt[(w * 16 + 8 + t) * SV4 + lane] = vreg1[t];
    __syncthreads();
    if (kt + 1 < ktiles) LOAD(kt + 1);

    const int k0 = kt * 64;
    const bool activeA = (kt <= qtA);

    f16x8 kf[4];
#pragma unroll
    for (int nt = 0; nt < 4; nt++) {
      f16x8 f = {};
      if (quad < 2) f = *(const f16x8*)&sK[(nt * 16 + l16) * SK4 + quad * 8];
      kf[nt] = f;
    }

    {
      const bool mask = (kt == qtB);
#pragma unroll
      for (int nt = 0; nt < 4; nt++) {
        f32x4 s = __builtin_amdgcn_mfma_f32_16x16x32_f16(
            qfragB, kf[nt], (f32x4){0.f, 0.f, 0.f, 0.f}, 0, 0, 0);
        const int gk = k0 + nt * 16 + l16;
#pragma unroll
        for (int r = 0; r < 4; r++) {
          float sv = s[r] * s[r] * 2.0f;
          if (mask) sv = (gk <= gqB + quad * 4 + r) ? sv : 0.0f;
          sS2B[(quad * 4 + r) * SS4 + nt * 16 + l16] = (_Float16)sv;
        }
      }
    }
    if (activeA) {
      const bool mask = (kt == qtA);
#pragma unroll
      for (int nt = 0; nt < 4; nt++) {
        f32x4 s = __builtin_amdgcn_mfma_f32_16x16x32_f16(
            qfragA, kf[nt], (f32x4){0.f, 0.f, 0.f, 0.f}, 0, 0, 0);
        const int gk = k0 + nt * 16 + l16;
#pragma unroll
        for (int r = 0; r < 4; r++) {
          float sv = s[r] * s[r] * 2.0f;
          if (mask) sv = (gk <= gqA + quad * 4 + r) ? sv : 0.0f;
          sS2A[(quad * 4 + r) * SS4 + nt * 16 + l16] = (_Float16)sv;
        }
      }
    }
    __asm__ volatile("s_waitcnt lgkmcnt(0)" ::: "memory");

    f16x8 afB0 = *(const f16x8*)&sS2B[l16 * SS4 + quad * 8];
    f16x8 afB1 = *(const f16x8*)&sS2B[l16 * SS4 + 32 + quad * 8];
    f16x8 afA0 = {}, afA1 = {};
    if (activeA) {
      afA0 = *(const f16x8*)&sS2A[l16 * SS4 + quad * 8];
      afA1 = *(const f16x8*)&sS2A[l16 * SS4 + 32 + quad * 8];
    }

#pragma unroll
    for (int nt = 0; nt < 4; nt++) {
      f16x8 vf0 = *(const f16x8*)&sVt[(nt * 16 + l16) * SV4 + quad * 8];
      f16x8 vf1 = *(const f16x8*)&sVt[(nt * 16 + l16) * SV4 + 32 + quad * 8];
      oaccB[nt] = __builtin_amdgcn_mfma_f32_16x16x32_f16(afB0, vf0, oaccB[nt], 0, 0, 0);
      oaccB[nt] = __builtin_amdgcn_mfma_f32_16x16x32_f16(afB1, vf1, oaccB[nt], 0, 0, 0);
      if (activeA) {
        oaccA[nt] = __builtin_amdgcn_mfma_f32_16x16x32_f16(afA0, vf0, oaccA[nt], 0, 0, 0);
        oaccA[nt] = __builtin_amdgcn_mfma_f32_16x16x32_f16(afA1, vf1, oaccA[nt], 0, 0, 0);
      }
    }
    zaccB = __builtin_amdgcn_mfma_f32_16x16x32_f16(afB0, zf0, zaccB, 0, 0, 0);
    zaccB = __builtin_amdgcn_mfma_f32_16x16x32_f16(afB1, zf1, zaccB, 0, 0, 0);
    if (activeA) {
      zaccA = __builtin_amdgcn_mfma_f32_16x16x32_f16(afA0, zf0, zaccA, 0, 0, 0);
      zaccA = __builtin_amdgcn_mfma_f32_16x16x32_f16(afA1, zf1, zaccA, 0, 0, 0);
    }
  }

  {
    float rz[4];
#pragma unroll
    for (int r = 0; r < 4; r++) {
      float zz = __shfl(zaccB[r], lane & 48);
      rz[r] = 1.0f / (zz + 32.0f * EPS);
    }
#pragma unroll
    for (int nt = 0; nt < 4; nt++)
#pragma unroll
      for (int r = 0; r < 4; r++) {
        const int gq = gqB + quad * 4 + r;
        O[(size_t)(b * LL + gq) * (HH * HD) + h * HD + nt * 16 + l16] =
            (_Float16)(oaccB[nt][r] * rz[r]);
      }
  }
  {
    float rz[4];
#pragma unroll
    for (int r = 0; r < 4; r++) {
      float zz = __shfl(zaccA[r], lane & 48);
      rz[r] = 1.0f / (zz + 32.0f * EPS);
    }
#pragma unroll
    for (int nt = 0; nt < 4; nt++)
#pragma unroll
      for (int r = 0; r < 4; r++) {
        const int gq = gqA + quad * 4 + r;
        O[(size_t)(b * LL + gq) * (HH * HD) + h * HD + nt * 16 + l16] =
            (_Float16)(oaccA[nt][r] * rz[r]);
      }
  }
}

// ---------------------------------------------------------------------------
// fix_final: exact fp32 ratio for the first NFIX positions per (b,h).
// Standalone launch — round 15 proved fusing this into the attention grid
// costs 24% on the attention kernel.
// ---------------------------------------------------------------------------
__global__ __launch_bounds__(256) void fix_final(
    const float* __restrict__ QKVe, _Float16* __restrict__ Oatt) {
  const int b = blockIdx.x >> 4, h = blockIdx.x & 15;
  const int tid = threadIdx.x;
  const int p = tid >> 6, d = tid & 63;

  float num = 0.f, z = 0.f;
  const float* qrow = QKVe + (size_t)(b * 4 + p) * RQKV + h * FD;
  for (int j = 0; j <= p; j++) {
    const float* krow = QKVe + (size_t)(b * 4 + j) * RQKV + 256 + h * FD;
    float s = 0.f;
#pragma unroll
    for (int f = 0; f < FD; f++) s += qrow[f] * krow[f];
    s *= 0.25f;
    s = s * s;
    z += s;
    num += s * QKVe[(size_t)(b * 4 + j) * RQKV + 512 + h * HD + d];
  }
  Oatt[(size_t)(b * LL + p) * (HH * HD) + h * HD + d] =
      (_Float16)(num / (z + EPS));
}

// ---------------------------------------------------------------------------
// Launch: 5 kernels.
// ---------------------------------------------------------------------------
extern "C" void kernel_launch(void* const* d_in, const int* in_sizes, int n_in,
                              void* d_out, int out_size, void* d_ws, size_t ws_size,
                              hipStream_t stream) {
  const float* hs = (const float*)d_in[0];  // [4096, 1024]
  const float* Wq = (const float*)d_in[1];  // [1024, 256]
  const float* Wk = (const float*)d_in[2];  // [1024, 256]
  const float* Wv = (const float*)d_in[3];  // [1024, 1024]
  const float* Wo = (const float*)d_in[4];  // [1024, 1024]
  float* out = (float*)d_out;               // [4096, 1024]

  char* ws = (char*)d_ws;
  _Float16* WqkvT = (_Float16*)ws;                    // [1536][1024] = 3 MiB
  _Float16* WoT   = (_Float16*)(ws + (3ull << 20));   // [1024][1024] = 2 MiB
  _Float16* HS16  = (_Float16*)(ws + (5ull << 20));   // [4096][1024] = 8 MiB
  _Float16* QKV   = (_Float16*)(ws + (13ull << 20));  // [4096][1536] = 12 MiB
  _Float16* Oatt  = (_Float16*)(ws + (25ull << 20));  // [4096][1024] = 8 MiB
  float*    QKVe  = (float*)(ws + (33ull << 20));     // [8][1536] fp32

  const int M = BB * LL;  // 4096

  // prep: W transposes + fp32 early-QKV + hs fp32->fp16 cast (one launch)
  prep<<<dim3(3632), 256, 0, stream>>>(Wq, Wk, Wv, Wo, hs, WqkvT, WoT, QKVe, HS16);

  // fused QKV projection: 64x64 tiles -> 1536 blocks (6/CU)
  gemm_f16<_Float16><<<dim3(RQKV / 64, M / 64), 256, 0, stream>>>(
      HS16, WqkvT, QKV, M, RQKV, DD);

  // attention (512 perfectly balanced blocks — do not add grid columns)
  attn_mfma4<<<dim3(LL / 128, BB * HH), 256, 0, stream>>>(QKV, Oatt);

  // fp32-exact first-NFIX rows per (b,h)
  fix_final<<<dim3(BB * HH), 256, 0, stream>>>(QKVe, Oatt);

  // output projection: 64x64 tiles -> 1024 blocks (4/CU)
  gemm_f16<float><<<dim3(DD / 64, M / 64), 256, 0, stream>>>(
      Oatt, WoT, out, M, DD, DD);
}

// Round 18
// 175.220 us; speedup vs baseline: 1.0532x; 1.0532x over previous
//
#include <hip/hip_runtime.h>
#include <hip/hip_bf16.h>

// Problem constants
#define BB 2
#define LL 2048
#define DD 1024
#define HH 16
#define FD 16
#define HD 64
#define EPS 1e-5f
#define RQKV 1536   // fused QKV row stride (256 Q + 256 K + 1024 V)
#define NFIX 4      // first NFIX positions per (b,h) recomputed in fp32 (low-z rows)

typedef __attribute__((ext_vector_type(4))) float f32x4;
typedef __attribute__((ext_vector_type(8))) _Float16 f16x8;
typedef __attribute__((ext_vector_type(4))) _Float16 f16x4;

// ---------------------------------------------------------------------------
// prep: fused pre-pass, branch on block range (round-15/16 verified).
//   [0,1536):    transpose+cast [Wq|Wk|Wv] -> WqkvT fp16 [1536][1024]
//   [1536,2560): transpose+cast Wo -> WoT fp16 [1024][1024]
//   [2560,2608): early_qkv — QKVe[8][1536] = hs_early[8][1024] @ W, fp32
//     (early rows must come from fp32 inputs: fp16-sourced q,k give |ds|~4e-4,
//      which s^2/(z+eps) amplifies to ~0.1 output error on low-z rows.)
//   [2608,3632): cast hs fp32 -> HS16 fp16 (shared A operand pre-cast ONCE —
//      round 14 proved folding this into the multi-reuse GEMM doubles HBM).
// ---------------------------------------------------------------------------
__global__ __launch_bounds__(256) void prep(
    const float* __restrict__ Wq, const float* __restrict__ Wk,
    const float* __restrict__ Wv, const float* __restrict__ Wo,
    const float* __restrict__ hs, _Float16* __restrict__ WqkvT,
    _Float16* __restrict__ WoT, float* __restrict__ QKVe,
    _Float16* __restrict__ HS16) {
  __shared__ __attribute__((aligned(16))) char smem[40960];
  const int bx = blockIdx.x;
  const int tid = threadIdx.x;

  if (bx >= 2608) {
    // ---- cast_hs path ----
    int idx = ((bx - 2608) * 256 + tid) * 16;
#pragma unroll
    for (int half = 0; half < 2; half++) {
      float4 a = *(const float4*)(hs + idx + half * 8);
      float4 b = *(const float4*)(hs + idx + half * 8 + 4);
      f16x8 p = {(_Float16)a.x, (_Float16)a.y, (_Float16)a.z, (_Float16)a.w,
                 (_Float16)b.x, (_Float16)b.y, (_Float16)b.z, (_Float16)b.w};
      *(f16x8*)(HS16 + idx + half * 8) = p;
    }
    return;
  }

  if (bx < 2560) {
    // ---- transpose+cast path ----
    _Float16(*s)[40] = (_Float16(*)[40])smem;
    const float* src;
    _Float16* dst;
    int n0, ncol, drow, k0;
    if (bx < 1536) {
      int ct = bx % 48, kt = bx / 48;
      if (ct < 8) { src = Wq; n0 = ct * 32; ncol = 256; drow = n0; }
      else if (ct < 16) { src = Wk; n0 = (ct - 8) * 32; ncol = 256; drow = 256 + n0; }
      else { src = Wv; n0 = (ct - 16) * 32; ncol = 1024; drow = 512 + n0; }
      k0 = kt * 32;
      dst = WqkvT;
    } else {
      int i2 = bx - 1536;
      n0 = (i2 & 31) * 32; k0 = (i2 >> 5) * 32;
      src = Wo; ncol = DD; drow = n0; dst = WoT;
    }
    {
      int r = tid >> 3, c = (tid & 7) * 4;
      float4 v = *(const float4*)(src + (size_t)(k0 + r) * ncol + n0 + c);
      f16x4 p = {(_Float16)v.x, (_Float16)v.y, (_Float16)v.z, (_Float16)v.w};
      *(f16x4*)&s[r][c] = p;
    }
    __syncthreads();
    {
      int n = tid >> 3, kk = (tid & 7) * 4;
      f16x4 o = {s[kk + 0][n], s[kk + 1][n], s[kk + 2][n], s[kk + 3][n]};
      *(f16x4*)(dst + (size_t)(drow + n) * DD + k0 + kk) = o;
    }
    return;
  }

  // ---- early_qkv path ----
  float(*sHS)[DD] = (float(*)[DD])smem;                      // 32 KB
  float(*part)[8][32] = (float(*)[8][32])(smem + 32768);     // 8 KB
  const int kg = tid >> 5, c = tid & 31;
  const int c0 = (bx - 2560) * 32;

  for (int i = tid; i < 8 * (DD / 4); i += 256) {
    int e = i / (DD / 4), col4 = (i % (DD / 4)) * 4;
    int b = e >> 2, r = e & 3;
    *(float4*)&sHS[e][col4] =
        *(const float4*)(hs + (size_t)(b * LL + r) * DD + col4);
  }
  __syncthreads();

  const float* W;
  int col, ncol;
  if (c0 < 256) { W = Wq; col = c0 + c; ncol = 256; }
  else if (c0 < 512) { W = Wk; col = (c0 - 256) + c; ncol = 256; }
  else { W = Wv; col = (c0 - 512) + c; ncol = 1024; }

  float acc[8] = {};
  const int d0 = kg * 128;
#pragma unroll 4
  for (int d = d0; d < d0 + 128; d++) {
    float wv = W[(size_t)d * ncol + col];
#pragma unroll
    for (int e = 0; e < 8; e++) acc[e] += sHS[e][d] * wv;
  }
#pragma unroll
  for (int e = 0; e < 8; e++) part[kg][e][c] = acc[e];
  __syncthreads();

  {
    int e = tid >> 5;
    float t = 0.f;
#pragma unroll
    for (int g = 0; g < 8; g++) t += part[g][e][c];
    QKVe[(size_t)e * RQKV + c0 + c] = t;
  }
}

// ---------------------------------------------------------------------------
// fp16 MFMA GEMM (round-13/16 verified, byte-identical): C = A @ Bt^T.
// 128x64 tile, BK=64, 4 waves (2x2, wave tile 64x32), register prefetch of
// the next 64-K slab. XOR-swizzled LDS (no pad). Rounds 12/14/17 measured
// that DMA staging, fused fp32-A, and 64x64 tiles ALL regress this kernel —
// do not perturb without counters.
// ---------------------------------------------------------------------------
template <typename OutT>
__global__ __launch_bounds__(256) void gemm_f16(
    const _Float16* __restrict__ A, const _Float16* __restrict__ Bt,
    OutT* __restrict__ C, int M, int N, int K) {
  __shared__ __attribute__((aligned(16))) _Float16 sA[128 * 64];  // 16 KB
  __shared__ __attribute__((aligned(16))) _Float16 sB[64 * 64];   // 8 KB
  const int tid = threadIdx.x;
  const int m0 = blockIdx.y * 128, n0 = blockIdx.x * 64;
  const int w = tid >> 6, lane = tid & 63, quad = lane >> 4, l16 = lane & 15;
  const int wm = (w >> 1) * 64, wn = (w & 1) * 32;

  const int sr = tid >> 1, p = tid & 1;     // A: row 0..127, half p
  const int brow = (tid & 127) >> 1;        // B: row 0..63
  const _Float16* Ag = A + (size_t)(m0 + sr) * K + p * 32;
  const _Float16* Bg = Bt + (size_t)(n0 + brow) * K + p * 32;
  _Float16* sAw = &sA[sr * 64];
  _Float16* sBw = &sB[brow * 64];
  const int aswz = sr & 7, bswz = brow & 7;

  f32x4 acc[4][2];
#pragma unroll
  for (int i = 0; i < 4; i++)
#pragma unroll
    for (int j = 0; j < 2; j++) acc[i][j] = (f32x4){0.f, 0.f, 0.f, 0.f};

  f16x8 ar[4], br[4];
  auto LOAD = [&](int k0) {
#pragma unroll
    for (int i = 0; i < 4; i++) ar[i] = *(const f16x8*)(Ag + k0 + i * 8);
    if (tid < 128) {
#pragma unroll
      for (int i = 0; i < 4; i++) br[i] = *(const f16x8*)(Bg + k0 + i * 8);
    }
  };
  LOAD(0);

  for (int k0 = 0; k0 < K; k0 += 64) {
    __syncthreads();
#pragma unroll
    for (int i = 0; i < 4; i++)
      *(f16x8*)(sAw + (((4 * p + i) ^ aswz) * 8)) = ar[i];
    if (tid < 128) {
#pragma unroll
      for (int i = 0; i < 4; i++)
        *(f16x8*)(sBw + (((4 * p + i) ^ bswz) * 8)) = br[i];
    }
    __syncthreads();
    if (k0 + 64 < K) LOAD(k0 + 64);  // prefetch overlaps the MFMAs below

#pragma unroll
    for (int s = 0; s < 2; s++) {
      f16x8 af[4], bf[2];
#pragma unroll
      for (int i = 0; i < 4; i++) {
        int row = wm + i * 16 + l16;
        int col = ((s * 4 + quad) ^ (row & 7)) * 8;
        af[i] = *(const f16x8*)&sA[row * 64 + col];
      }
#pragma unroll
      for (int j = 0; j < 2; j++) {
        int row = wn + j * 16 + l16;
        int col = ((s * 4 + quad) ^ (row & 7)) * 8;
        bf[j] = *(const f16x8*)&sB[row * 64 + col];
      }
#pragma unroll
      for (int i = 0; i < 4; i++)
#pragma unroll
        for (int j = 0; j < 2; j++)
          acc[i][j] = __builtin_amdgcn_mfma_f32_16x16x32_f16(af[i], bf[j], acc[i][j], 0, 0, 0);
    }
  }

#pragma unroll
  for (int i = 0; i < 4; i++)
#pragma unroll
    for (int j = 0; j < 2; j++)
#pragma unroll
      for (int r = 0; r < 4; r++) {
        const int row = m0 + wm + i * 16 + quad * 4 + r;
        const int col = n0 + wn + j * 16 + l16;
        C[(size_t)row * N + col] = (OutT)acc[i][j][r];
      }
}

// ---------------------------------------------------------------------------
// MFMA causal quadratic attention, v4 (round-13/16 verified) + sqrt2 prefold:
// Q fragments pre-scaled by sqrt(2) once per block, so sv = (sqrt2 q.k)^2 =
// 2*(q.k)^2 — identical scale bookkeeping to round 16 (o = num/(z+32*EPS)),
// but the per-element *2.0f (32 VALU/wave-ktile in the hottest loop) is gone.
// Paired complementary q-tiles; 512 perfectly balanced blocks (2/CU); round
// 15 proved adding grid columns costs 24% — keep grid exactly (16,32).
// z via MFMA against ones-row tile (sVt rows 64..79). Strides 88.
// ---------------------------------------------------------------------------
#define SK4 24
#define SV4 88
#define SS4 88

__global__ __launch_bounds__(256) void attn_mfma4(
    const _Float16* __restrict__ QKV, _Float16* __restrict__ O) {
  __shared__ __attribute__((aligned(16))) _Float16 sK[64 * SK4];
  __shared__ __attribute__((aligned(16))) _Float16 sVt[80 * SV4];
  __shared__ __attribute__((aligned(16))) _Float16 sS2[4 * 32 * SS4];

  const int bh = blockIdx.y;
  const int b = bh >> 4, h = bh & 15;
  const int qtA = blockIdx.x;
  const int qtB = 31 - qtA;
  const int tid = threadIdx.x;
  const int w = tid >> 6;
  const int lane = tid & 63;
  const int quad = lane >> 4;
  const int l16 = lane & 15;
  const int gqA = qtA * 64 + w * 16;
  const int gqB = qtB * 64 + w * 16;

  f16x8 qfragA = {}, qfragB = {};
  if (quad < 2) {
    qfragA = *(const f16x8*)(QKV +
        (size_t)(b * LL + gqA + l16) * RQKV + h * FD + quad * 8);
    qfragB = *(const f16x8*)(QKV +
        (size_t)(b * LL + gqB + l16) * RQKV + h * FD + quad * 8);
    const _Float16 RT2 = (_Float16)1.41421356f;
#pragma unroll
    for (int i = 0; i < 8; i++) {
      qfragA[i] = qfragA[i] * RT2;
      qfragB[i] = qfragB[i] * RT2;
    }
  }

  for (int t = tid; t < 16 * SV4; t += 256) {
    int r = t / SV4, c = t % SV4;
    sVt[64 * SV4 + t] = (_Float16)((r == 0 && c < 64) ? 1.0f : 0.0f);
  }
  __syncthreads();
  const f16x8 zf0 = *(const f16x8*)&sVt[(64 + l16) * SV4 + quad * 8];
  const f16x8 zf1 = *(const f16x8*)&sVt[(64 + l16) * SV4 + 32 + quad * 8];

  f32x4 oaccA[4], oaccB[4];
  f32x4 zaccA = (f32x4){0.f, 0.f, 0.f, 0.f};
  f32x4 zaccB = (f32x4){0.f, 0.f, 0.f, 0.f};
#pragma unroll
  for (int nt = 0; nt < 4; nt++) {
    oaccA[nt] = (f32x4){0.f, 0.f, 0.f, 0.f};
    oaccB[nt] = (f32x4){0.f, 0.f, 0.f, 0.f};
  }

  _Float16* sS2B = sS2 + w * 32 * SS4;
  _Float16* sS2A = sS2B + 16 * SS4;

  const int ktiles = qtB + 1;

  const int skey = tid >> 2, sfg = (tid & 3) * 4;
  uint2 kreg;
  f16x8 vreg0, vreg1;
  auto LOAD = [&](int kt) {
    kreg = *(const uint2*)(QKV +
        (size_t)(b * LL + kt * 64 + skey) * RQKV + 256 + h * FD + sfg);
    const _Float16* vp = QKV +
        (size_t)(b * LL + kt * 64 + lane) * RQKV + 512 + h * HD + w * 16;
    vreg0 = *(const f16x8*)vp;
    vreg1 = *(const f16x8*)(vp + 8);
  };
  LOAD(0);

  for (int kt = 0; kt < ktiles; kt++) {
    __syncthreads();
    *(uint2*)&sK[skey * SK4 + sfg] = kreg;
#pragma unroll
    for (int t = 0; t < 8; t++) sVt[(w * 16 + t) * SV4 + lane] = vreg0[t];
#pragma unroll
    for (int t = 0; t < 8; t++) sVt[(w * 16 + 8 + t) * SV4 + lane] = vreg1[t];
    __syncthreads();
    if (kt + 1 < ktiles) LOAD(kt + 1);

    const int k0 = kt * 64;
    const bool activeA = (kt <= qtA);

    f16x8 kf[4];
#pragma unroll
    for (int nt = 0; nt < 4; nt++) {
      f16x8 f = {};
      if (quad < 2) f = *(const f16x8*)&sK[(nt * 16 + l16) * SK4 + quad * 8];
      kf[nt] = f;
    }

    {
      const bool mask = (kt == qtB);
#pragma unroll
      for (int nt = 0; nt < 4; nt++) {
        f32x4 s = __builtin_amdgcn_mfma_f32_16x16x32_f16(
            qfragB, kf[nt], (f32x4){0.f, 0.f, 0.f, 0.f}, 0, 0, 0);
        const int gk = k0 + nt * 16 + l16;
#pragma unroll
        for (int r = 0; r < 4; r++) {
          float sv = s[r] * s[r];
          if (mask) sv = (gk <= gqB + quad * 4 + r) ? sv : 0.0f;
          sS2B[(quad * 4 + r) * SS4 + nt * 16 + l16] = (_Float16)sv;
        }
      }
    }
    if (activeA) {
      const bool mask = (kt == qtA);
#pragma unroll
      for (int nt = 0; nt < 4; nt++) {
        f32x4 s = __builtin_amdgcn_mfma_f32_16x16x32_f16(
            qfragA, kf[nt], (f32x4){0.f, 0.f, 0.f, 0.f}, 0, 0, 0);
        const int gk = k0 + nt * 16 + l16;
#pragma unroll
        for (int r = 0; r < 4; r++) {
          float sv = s[r] * s[r];
          if (mask) sv = (gk <= gqA + quad * 4 + r) ? sv : 0.0f;
          sS2A[(quad * 4 + r) * SS4 + nt * 16 + l16] = (_Float16)sv;
        }
      }
    }
    __asm__ volatile("s_waitcnt lgkmcnt(0)" ::: "memory");

    f16x8 afB0 = *(const f16x8*)&sS2B[l16 * SS4 + quad * 8];
    f16x8 afB1 = *(const f16x8*)&sS2B[l16 * SS4 + 32 + quad * 8];
    f16x8 afA0 = {}, afA1 = {};
    if (activeA) {
      afA0 = *(const f16x8*)&sS2A[l16 * SS4 + quad * 8];
      afA1 = *(const f16x8*)&sS2A[l16 * SS4 + 32 + quad * 8];
    }

#pragma unroll
    for (int nt = 0; nt < 4; nt++) {
      f16x8 vf0 = *(const f16x8*)&sVt[(nt * 16 + l16) * SV4 + quad * 8];
      f16x8 vf1 = *(const f16x8*)&sVt[(nt * 16 + l16) * SV4 + 32 + quad * 8];
      oaccB[nt] = __builtin_amdgcn_mfma_f32_16x16x32_f16(afB0, vf0, oaccB[nt], 0, 0, 0);
      oaccB[nt] = __builtin_amdgcn_mfma_f32_16x16x32_f16(afB1, vf1, oaccB[nt], 0, 0, 0);
      if (activeA) {
        oaccA[nt] = __builtin_amdgcn_mfma_f32_16x16x32_f16(afA0, vf0, oaccA[nt], 0, 0, 0);
        oaccA[nt] = __builtin_amdgcn_mfma_f32_16x16x32_f16(afA1, vf1, oaccA[nt], 0, 0, 0);
      }
    }
    zaccB = __builtin_amdgcn_mfma_f32_16x16x32_f16(afB0, zf0, zaccB, 0, 0, 0);
    zaccB = __builtin_amdgcn_mfma_f32_16x16x32_f16(afB1, zf1, zaccB, 0, 0, 0);
    if (activeA) {
      zaccA = __builtin_amdgcn_mfma_f32_16x16x32_f16(afA0, zf0, zaccA, 0, 0, 0);
      zaccA = __builtin_amdgcn_mfma_f32_16x16x32_f16(afA1, zf1, zaccA, 0, 0, 0);
    }
  }

  {
    float rz[4];
#pragma unroll
    for (int r = 0; r < 4; r++) {
      float zz = __shfl(zaccB[r], lane & 48);
      rz[r] = 1.0f / (zz + 32.0f * EPS);
    }
#pragma unroll
    for (int nt = 0; nt < 4; nt++)
#pragma unroll
      for (int r = 0; r < 4; r++) {
        const int gq = gqB + quad * 4 + r;
        O[(size_t)(b * LL + gq) * (HH * HD) + h * HD + nt * 16 + l16] =
            (_Float16)(oaccB[nt][r] * rz[r]);
      }
  }
  {
    float rz[4];
#pragma unroll
    for (int r = 0; r < 4; r++) {
      float zz = __shfl(zaccA[r], lane & 48);
      rz[r] = 1.0f / (zz + 32.0f * EPS);
    }
#pragma unroll
    for (int nt = 0; nt < 4; nt++)
#pragma unroll
      for (int r = 0; r < 4; r++) {
        const int gq = gqA + quad * 4 + r;
        O[(size_t)(b * LL + gq) * (HH * HD) + h * HD + nt * 16 + l16] =
            (_Float16)(oaccA[nt][r] * rz[r]);
      }
  }
}

// ---------------------------------------------------------------------------
// fix_final: exact fp32 ratio for the first NFIX positions per (b,h).
// Standalone launch — round 15 proved fusing this into the attention grid
// costs 24% on the attention kernel.
// ---------------------------------------------------------------------------
__global__ __launch_bounds__(256) void fix_final(
    const float* __restrict__ QKVe, _Float16* __restrict__ Oatt) {
  const int b = blockIdx.x >> 4, h = blockIdx.x & 15;
  const int tid = threadIdx.x;
  const int p = tid >> 6, d = tid & 63;

  float num = 0.f, z = 0.f;
  const float* qrow = QKVe + (size_t)(b * 4 + p) * RQKV + h * FD;
  for (int j = 0; j <= p; j++) {
    const float* krow = QKVe + (size_t)(b * 4 + j) * RQKV + 256 + h * FD;
    float s = 0.f;
#pragma unroll
    for (int f = 0; f < FD; f++) s += qrow[f] * krow[f];
    s *= 0.25f;
    s = s * s;
    z += s;
    num += s * QKVe[(size_t)(b * 4 + j) * RQKV + 512 + h * HD + d];
  }
  Oatt[(size_t)(b * LL + p) * (HH * HD) + h * HD + d] =
      (_Float16)(num / (z + EPS));
}

// ---------------------------------------------------------------------------
// Launch: 5 kernels.
// ---------------------------------------------------------------------------
extern "C" void kernel_launch(void* const* d_in, const int* in_sizes, int n_in,
                              void* d_out, int out_size, void* d_ws, size_t ws_size,
                              hipStream_t stream) {
  const float* hs = (const float*)d_in[0];  // [4096, 1024]
  const float* Wq = (const float*)d_in[1];  // [1024, 256]
  const float* Wk = (const float*)d_in[2];  // [1024, 256]
  const float* Wv = (const float*)d_in[3];  // [1024, 1024]
  const float* Wo = (const float*)d_in[4];  // [1024, 1024]
  float* out = (float*)d_out;               // [4096, 1024]

  char* ws = (char*)d_ws;
  _Float16* WqkvT = (_Float16*)ws;                    // [1536][1024] = 3 MiB
  _Float16* WoT   = (_Float16*)(ws + (3ull << 20));   // [1024][1024] = 2 MiB
  _Float16* HS16  = (_Float16*)(ws + (5ull << 20));   // [4096][1024] = 8 MiB
  _Float16* QKV   = (_Float16*)(ws + (13ull << 20));  // [4096][1536] = 12 MiB
  _Float16* Oatt  = (_Float16*)(ws + (25ull << 20));  // [4096][1024] = 8 MiB
  float*    QKVe  = (float*)(ws + (33ull << 20));     // [8][1536] fp32

  const int M = BB * LL;  // 4096

  // prep: W transposes + fp32 early-QKV + hs fp32->fp16 cast (one launch)
  prep<<<dim3(3632), 256, 0, stream>>>(Wq, Wk, Wv, Wo, hs, WqkvT, WoT, QKVe, HS16);

  // fused QKV projection: 128x64 tiles (round-16 verified optimum)
  gemm_f16<_Float16><<<dim3(RQKV / 64, M / 128), 256, 0, stream>>>(
      HS16, WqkvT, QKV, M, RQKV, DD);

  // attention (512 perfectly balanced blocks — do not add grid columns)
  attn_mfma4<<<dim3(LL / 128, BB * HH), 256, 0, stream>>>(QKV, Oatt);

  // fp32-exact first-NFIX rows per (b,h)
  fix_final<<<dim3(BB * HH), 256, 0, stream>>>(QKVe, Oatt);

  // output projection: 128x64 tiles
  gemm_f16<float><<<dim3(DD / 64, M / 128), 256, 0, stream>>>(
      Oatt, WoT, out, M, DD, DD);
}

// Round 19
// 172.482 us; speedup vs baseline: 1.0700x; 1.0159x over previous
//
#include <hip/hip_runtime.h>
#include <hip/hip_bf16.h>

// Problem constants
#define BB 2
#define LL 2048
#define DD 1024
#define HH 16
#define FD 16
#define HD 64
#define EPS 1e-5f
#define RQKV 1536   // fused QKV row stride (256 Q + 256 K + 1024 V)
#define NFIX 4      // first NFIX positions per (b,h) recomputed in fp32 (low-z rows)

typedef __attribute__((ext_vector_type(4))) float f32x4;
typedef __attribute__((ext_vector_type(8))) _Float16 f16x8;
typedef __attribute__((ext_vector_type(4))) _Float16 f16x4;

// ---------------------------------------------------------------------------
// prep: fused pre-pass, branch on block range (round-15/16 verified).
//   [0,1536):    transpose+cast [Wq|Wk|Wv] -> WqkvT fp16 [1536][1024]
//   [1536,2560): transpose+cast Wo -> WoT fp16 [1024][1024]
//   [2560,2608): early_qkv — QKVe[8][1536] = hs_early[8][1024] @ W, fp32
//     (early rows must come from fp32 inputs: fp16-sourced q,k give |ds|~4e-4,
//      which s^2/(z+eps) amplifies to ~0.1 output error on low-z rows.)
//   [2608,3632): cast hs fp32 -> HS16 fp16 (shared A operand pre-cast ONCE —
//      round 14 proved folding this into the multi-reuse GEMM doubles HBM).
// ---------------------------------------------------------------------------
__global__ __launch_bounds__(256) void prep(
    const float* __restrict__ Wq, const float* __restrict__ Wk,
    const float* __restrict__ Wv, const float* __restrict__ Wo,
    const float* __restrict__ hs, _Float16* __restrict__ WqkvT,
    _Float16* __restrict__ WoT, float* __restrict__ QKVe,
    _Float16* __restrict__ HS16) {
  __shared__ __attribute__((aligned(16))) char smem[40960];
  const int bx = blockIdx.x;
  const int tid = threadIdx.x;

  if (bx >= 2608) {
    // ---- cast_hs path ----
    int idx = ((bx - 2608) * 256 + tid) * 16;
#pragma unroll
    for (int half = 0; half < 2; half++) {
      float4 a = *(const float4*)(hs + idx + half * 8);
      float4 b = *(const float4*)(hs + idx + half * 8 + 4);
      f16x8 p = {(_Float16)a.x, (_Float16)a.y, (_Float16)a.z, (_Float16)a.w,
                 (_Float16)b.x, (_Float16)b.y, (_Float16)b.z, (_Float16)b.w};
      *(f16x8*)(HS16 + idx + half * 8) = p;
    }
    return;
  }

  if (bx < 2560) {
    // ---- transpose+cast path ----
    _Float16(*s)[40] = (_Float16(*)[40])smem;
    const float* src;
    _Float16* dst;
    int n0, ncol, drow, k0;
    if (bx < 1536) {
      int ct = bx % 48, kt = bx / 48;
      if (ct < 8) { src = Wq; n0 = ct * 32; ncol = 256; drow = n0; }
      else if (ct < 16) { src = Wk; n0 = (ct - 8) * 32; ncol = 256; drow = 256 + n0; }
      else { src = Wv; n0 = (ct - 16) * 32; ncol = 1024; drow = 512 + n0; }
      k0 = kt * 32;
      dst = WqkvT;
    } else {
      int i2 = bx - 1536;
      n0 = (i2 & 31) * 32; k0 = (i2 >> 5) * 32;
      src = Wo; ncol = DD; drow = n0; dst = WoT;
    }
    {
      int r = tid >> 3, c = (tid & 7) * 4;
      float4 v = *(const float4*)(src + (size_t)(k0 + r) * ncol + n0 + c);
      f16x4 p = {(_Float16)v.x, (_Float16)v.y, (_Float16)v.z, (_Float16)v.w};
      *(f16x4*)&s[r][c] = p;
    }
    __syncthreads();
    {
      int n = tid >> 3, kk = (tid & 7) * 4;
      f16x4 o = {s[kk + 0][n], s[kk + 1][n], s[kk + 2][n], s[kk + 3][n]};
      *(f16x4*)(dst + (size_t)(drow + n) * DD + k0 + kk) = o;
    }
    return;
  }

  // ---- early_qkv path ----
  float(*sHS)[DD] = (float(*)[DD])smem;                      // 32 KB
  float(*part)[8][32] = (float(*)[8][32])(smem + 32768);     // 8 KB
  const int kg = tid >> 5, c = tid & 31;
  const int c0 = (bx - 2560) * 32;

  for (int i = tid; i < 8 * (DD / 4); i += 256) {
    int e = i / (DD / 4), col4 = (i % (DD / 4)) * 4;
    int b = e >> 2, r = e & 3;
    *(float4*)&sHS[e][col4] =
        *(const float4*)(hs + (size_t)(b * LL + r) * DD + col4);
  }
  __syncthreads();

  const float* W;
  int col, ncol;
  if (c0 < 256) { W = Wq; col = c0 + c; ncol = 256; }
  else if (c0 < 512) { W = Wk; col = (c0 - 256) + c; ncol = 256; }
  else { W = Wv; col = (c0 - 512) + c; ncol = 1024; }

  float acc[8] = {};
  const int d0 = kg * 128;
#pragma unroll 4
  for (int d = d0; d < d0 + 128; d++) {
    float wv = W[(size_t)d * ncol + col];
#pragma unroll
    for (int e = 0; e < 8; e++) acc[e] += sHS[e][d] * wv;
  }
#pragma unroll
  for (int e = 0; e < 8; e++) part[kg][e][c] = acc[e];
  __syncthreads();

  {
    int e = tid >> 5;
    float t = 0.f;
#pragma unroll
    for (int g = 0; g < 8; g++) t += part[g][e][c];
    QKVe[(size_t)e * RQKV + c0 + c] = t;
  }
}

// ---------------------------------------------------------------------------
// fp16 MFMA GEMM (round-13/16 verified, byte-identical): C = A @ Bt^T.
// 128x64 tile, BK=64, 4 waves (2x2, wave tile 64x32), register prefetch of
// the next 64-K slab. XOR-swizzled LDS (no pad). Rounds 12/14/17 measured
// that DMA staging, fused fp32-A, and 64x64 tiles ALL regress this kernel —
// do not perturb without counters.
// ---------------------------------------------------------------------------
template <typename OutT>
__global__ __launch_bounds__(256) void gemm_f16(
    const _Float16* __restrict__ A, const _Float16* __restrict__ Bt,
    OutT* __restrict__ C, int M, int N, int K) {
  __shared__ __attribute__((aligned(16))) _Float16 sA[128 * 64];  // 16 KB
  __shared__ __attribute__((aligned(16))) _Float16 sB[64 * 64];   // 8 KB
  const int tid = threadIdx.x;
  const int m0 = blockIdx.y * 128, n0 = blockIdx.x * 64;
  const int w = tid >> 6, lane = tid & 63, quad = lane >> 4, l16 = lane & 15;
  const int wm = (w >> 1) * 64, wn = (w & 1) * 32;

  const int sr = tid >> 1, p = tid & 1;     // A: row 0..127, half p
  const int brow = (tid & 127) >> 1;        // B: row 0..63
  const _Float16* Ag = A + (size_t)(m0 + sr) * K + p * 32;
  const _Float16* Bg = Bt + (size_t)(n0 + brow) * K + p * 32;
  _Float16* sAw = &sA[sr * 64];
  _Float16* sBw = &sB[brow * 64];
  const int aswz = sr & 7, bswz = brow & 7;

  f32x4 acc[4][2];
#pragma unroll
  for (int i = 0; i < 4; i++)
#pragma unroll
    for (int j = 0; j < 2; j++) acc[i][j] = (f32x4){0.f, 0.f, 0.f, 0.f};

  f16x8 ar[4], br[4];
  auto LOAD = [&](int k0) {
#pragma unroll
    for (int i = 0; i < 4; i++) ar[i] = *(const f16x8*)(Ag + k0 + i * 8);
    if (tid < 128) {
#pragma unroll
      for (int i = 0; i < 4; i++) br[i] = *(const f16x8*)(Bg + k0 + i * 8);
    }
  };
  LOAD(0);

  for (int k0 = 0; k0 < K; k0 += 64) {
    __syncthreads();
#pragma unroll
    for (int i = 0; i < 4; i++)
      *(f16x8*)(sAw + (((4 * p + i) ^ aswz) * 8)) = ar[i];
    if (tid < 128) {
#pragma unroll
      for (int i = 0; i < 4; i++)
        *(f16x8*)(sBw + (((4 * p + i) ^ bswz) * 8)) = br[i];
    }
    __syncthreads();
    if (k0 + 64 < K) LOAD(k0 + 64);  // prefetch overlaps the MFMAs below

#pragma unroll
    for (int s = 0; s < 2; s++) {
      f16x8 af[4], bf[2];
#pragma unroll
      for (int i = 0; i < 4; i++) {
        int row = wm + i * 16 + l16;
        int col = ((s * 4 + quad) ^ (row & 7)) * 8;
        af[i] = *(const f16x8*)&sA[row * 64 + col];
      }
#pragma unroll
      for (int j = 0; j < 2; j++) {
        int row = wn + j * 16 + l16;
        int col = ((s * 4 + quad) ^ (row & 7)) * 8;
        bf[j] = *(const f16x8*)&sB[row * 64 + col];
      }
#pragma unroll
      for (int i = 0; i < 4; i++)
#pragma unroll
        for (int j = 0; j < 2; j++)
          acc[i][j] = __builtin_amdgcn_mfma_f32_16x16x32_f16(af[i], bf[j], acc[i][j], 0, 0, 0);
    }
  }

#pragma unroll
  for (int i = 0; i < 4; i++)
#pragma unroll
    for (int j = 0; j < 2; j++)
#pragma unroll
      for (int r = 0; r < 4; r++) {
        const int row = m0 + wm + i * 16 + quad * 4 + r;
        const int col = n0 + wn + j * 16 + l16;
        C[(size_t)row * N + col] = (OutT)acc[i][j][r];
      }
}

// ---------------------------------------------------------------------------
// MFMA causal quadratic attention, v4 + sqrt2 prefold + XCD-locality swizzle.
// Round-19 change: grid is (bh=32, pair=16) instead of (pair, bh) — the
// linearized block index is bh-major mod 8, so all 16 pair-blocks of one
// (b,h) (which share the same 320 KB of K/V) land on ONE XCD's L2 instead of
// being scattered over 8. FETCH_SIZE showed 37.6 MB vs ~13 ideal (3x
// over-fetch); better L2 hits shrink the exposed prefetch-miss latency.
// Kernel body identical to round 18. Round 15 proved extra grid columns
// regress 24% — grid stays exactly 512 blocks.
// ---------------------------------------------------------------------------
#define SK4 24
#define SV4 88
#define SS4 88

__global__ __launch_bounds__(256) void attn_mfma4(
    const _Float16* __restrict__ QKV, _Float16* __restrict__ O) {
  __shared__ __attribute__((aligned(16))) _Float16 sK[64 * SK4];
  __shared__ __attribute__((aligned(16))) _Float16 sVt[80 * SV4];
  __shared__ __attribute__((aligned(16))) _Float16 sS2[4 * 32 * SS4];

  const int bh = blockIdx.x;           // swizzle: bh is the fast grid dim
  const int b = bh >> 4, h = bh & 15;
  const int qtA = blockIdx.y;
  const int qtB = 31 - qtA;
  const int tid = threadIdx.x;
  const int w = tid >> 6;
  const int lane = tid & 63;
  const int quad = lane >> 4;
  const int l16 = lane & 15;
  const int gqA = qtA * 64 + w * 16;
  const int gqB = qtB * 64 + w * 16;

  f16x8 qfragA = {}, qfragB = {};
  if (quad < 2) {
    qfragA = *(const f16x8*)(QKV +
        (size_t)(b * LL + gqA + l16) * RQKV + h * FD + quad * 8);
    qfragB = *(const f16x8*)(QKV +
        (size_t)(b * LL + gqB + l16) * RQKV + h * FD + quad * 8);
    const _Float16 RT2 = (_Float16)1.41421356f;
#pragma unroll
    for (int i = 0; i < 8; i++) {
      qfragA[i] = qfragA[i] * RT2;
      qfragB[i] = qfragB[i] * RT2;
    }
  }

  for (int t = tid; t < 16 * SV4; t += 256) {
    int r = t / SV4, c = t % SV4;
    sVt[64 * SV4 + t] = (_Float16)((r == 0 && c < 64) ? 1.0f : 0.0f);
  }
  __syncthreads();
  const f16x8 zf0 = *(const f16x8*)&sVt[(64 + l16) * SV4 + quad * 8];
  const f16x8 zf1 = *(const f16x8*)&sVt[(64 + l16) * SV4 + 32 + quad * 8];

  f32x4 oaccA[4], oaccB[4];
  f32x4 zaccA = (f32x4){0.f, 0.f, 0.f, 0.f};
  f32x4 zaccB = (f32x4){0.f, 0.f, 0.f, 0.f};
#pragma unroll
  for (int nt = 0; nt < 4; nt++) {
    oaccA[nt] = (f32x4){0.f, 0.f, 0.f, 0.f};
    oaccB[nt] = (f32x4){0.f, 0.f, 0.f, 0.f};
  }

  _Float16* sS2B = sS2 + w * 32 * SS4;
  _Float16* sS2A = sS2B + 16 * SS4;

  const int ktiles = qtB + 1;

  const int skey = tid >> 2, sfg = (tid & 3) * 4;
  uint2 kreg;
  f16x8 vreg0, vreg1;
  auto LOAD = [&](int kt) {
    kreg = *(const uint2*)(QKV +
        (size_t)(b * LL + kt * 64 + skey) * RQKV + 256 + h * FD + sfg);
    const _Float16* vp = QKV +
        (size_t)(b * LL + kt * 64 + lane) * RQKV + 512 + h * HD + w * 16;
    vreg0 = *(const f16x8*)vp;
    vreg1 = *(const f16x8*)(vp + 8);
  };
  LOAD(0);

  for (int kt = 0; kt < ktiles; kt++) {
    __syncthreads();
    *(uint2*)&sK[skey * SK4 + sfg] = kreg;
#pragma unroll
    for (int t = 0; t < 8; t++) sVt[(w * 16 + t) * SV4 + lane] = vreg0[t];
#pragma unroll
    for (int t = 0; t < 8; t++) sVt[(w * 16 + 8 + t) * SV4 + lane] = vreg1[t];
    __syncthreads();
    if (kt + 1 < ktiles) LOAD(kt + 1);

    const int k0 = kt * 64;
    const bool activeA = (kt <= qtA);

    f16x8 kf[4];
#pragma unroll
    for (int nt = 0; nt < 4; nt++) {
      f16x8 f = {};
      if (quad < 2) f = *(const f16x8*)&sK[(nt * 16 + l16) * SK4 + quad * 8];
      kf[nt] = f;
    }

    {
      const bool mask = (kt == qtB);
#pragma unroll
      for (int nt = 0; nt < 4; nt++) {
        f32x4 s = __builtin_amdgcn_mfma_f32_16x16x32_f16(
            qfragB, kf[nt], (f32x4){0.f, 0.f, 0.f, 0.f}, 0, 0, 0);
        const int gk = k0 + nt * 16 + l16;
#pragma unroll
        for (int r = 0; r < 4; r++) {
          float sv = s[r] * s[r];
          if (mask) sv = (gk <= gqB + quad * 4 + r) ? sv : 0.0f;
          sS2B[(quad * 4 + r) * SS4 + nt * 16 + l16] = (_Float16)sv;
        }
      }
    }
    if (activeA) {
      const bool mask = (kt == qtA);
#pragma unroll
      for (int nt = 0; nt < 4; nt++) {
        f32x4 s = __builtin_amdgcn_mfma_f32_16x16x32_f16(
            qfragA, kf[nt], (f32x4){0.f, 0.f, 0.f, 0.f}, 0, 0, 0);
        const int gk = k0 + nt * 16 + l16;
#pragma unroll
        for (int r = 0; r < 4; r++) {
          float sv = s[r] * s[r];
          if (mask) sv = (gk <= gqA + quad * 4 + r) ? sv : 0.0f;
          sS2A[(quad * 4 + r) * SS4 + nt * 16 + l16] = (_Float16)sv;
        }
      }
    }
    __asm__ volatile("s_waitcnt lgkmcnt(0)" ::: "memory");

    f16x8 afB0 = *(const f16x8*)&sS2B[l16 * SS4 + quad * 8];
    f16x8 afB1 = *(const f16x8*)&sS2B[l16 * SS4 + 32 + quad * 8];
    f16x8 afA0 = {}, afA1 = {};
    if (activeA) {
      afA0 = *(const f16x8*)&sS2A[l16 * SS4 + quad * 8];
      afA1 = *(const f16x8*)&sS2A[l16 * SS4 + 32 + quad * 8];
    }

#pragma unroll
    for (int nt = 0; nt < 4; nt++) {
      f16x8 vf0 = *(const f16x8*)&sVt[(nt * 16 + l16) * SV4 + quad * 8];
      f16x8 vf1 = *(const f16x8*)&sVt[(nt * 16 + l16) * SV4 + 32 + quad * 8];
      oaccB[nt] = __builtin_amdgcn_mfma_f32_16x16x32_f16(afB0, vf0, oaccB[nt], 0, 0, 0);
      oaccB[nt] = __builtin_amdgcn_mfma_f32_16x16x32_f16(afB1, vf1, oaccB[nt], 0, 0, 0);
      if (activeA) {
        oaccA[nt] = __builtin_amdgcn_mfma_f32_16x16x32_f16(afA0, vf0, oaccA[nt], 0, 0, 0);
        oaccA[nt] = __builtin_amdgcn_mfma_f32_16x16x32_f16(afA1, vf1, oaccA[nt], 0, 0, 0);
      }
    }
    zaccB = __builtin_amdgcn_mfma_f32_16x16x32_f16(afB0, zf0, zaccB, 0, 0, 0);
    zaccB = __builtin_amdgcn_mfma_f32_16x16x32_f16(afB1, zf1, zaccB, 0, 0, 0);
    if (activeA) {
      zaccA = __builtin_amdgcn_mfma_f32_16x16x32_f16(afA0, zf0, zaccA, 0, 0, 0);
      zaccA = __builtin_amdgcn_mfma_f32_16x16x32_f16(afA1, zf1, zaccA, 0, 0, 0);
    }
  }

  {
    float rz[4];
#pragma unroll
    for (int r = 0; r < 4; r++) {
      float zz = __shfl(zaccB[r], lane & 48);
      rz[r] = 1.0f / (zz + 32.0f * EPS);
    }
#pragma unroll
    for (int nt = 0; nt < 4; nt++)
#pragma unroll
      for (int r = 0; r < 4; r++) {
        const int gq = gqB + quad * 4 + r;
        O[(size_t)(b * LL + gq) * (HH * HD) + h * HD + nt * 16 + l16] =
            (_Float16)(oaccB[nt][r] * rz[r]);
      }
  }
  {
    float rz[4];
#pragma unroll
    for (int r = 0; r < 4; r++) {
      float zz = __shfl(zaccA[r], lane & 48);
      rz[r] = 1.0f / (zz + 32.0f * EPS);
    }
#pragma unroll
    for (int nt = 0; nt < 4; nt++)
#pragma unroll
      for (int r = 0; r < 4; r++) {
        const int gq = gqA + quad * 4 + r;
        O[(size_t)(b * LL + gq) * (HH * HD) + h * HD + nt * 16 + l16] =
            (_Float16)(oaccA[nt][r] * rz[r]);
      }
  }
}

// ---------------------------------------------------------------------------
// fix_final: exact fp32 ratio for the first NFIX positions per (b,h).
// Standalone launch — round 15 proved fusing this into the attention grid
// costs 24% on the attention kernel.
// ---------------------------------------------------------------------------
__global__ __launch_bounds__(256) void fix_final(
    const float* __restrict__ QKVe, _Float16* __restrict__ Oatt) {
  const int b = blockIdx.x >> 4, h = blockIdx.x & 15;
  const int tid = threadIdx.x;
  const int p = tid >> 6, d = tid & 63;

  float num = 0.f, z = 0.f;
  const float* qrow = QKVe + (size_t)(b * 4 + p) * RQKV + h * FD;
  for (int j = 0; j <= p; j++) {
    const float* krow = QKVe + (size_t)(b * 4 + j) * RQKV + 256 + h * FD;
    float s = 0.f;
#pragma unroll
    for (int f = 0; f < FD; f++) s += qrow[f] * krow[f];
    s *= 0.25f;
    s = s * s;
    z += s;
    num += s * QKVe[(size_t)(b * 4 + j) * RQKV + 512 + h * HD + d];
  }
  Oatt[(size_t)(b * LL + p) * (HH * HD) + h * HD + d] =
      (_Float16)(num / (z + EPS));
}

// ---------------------------------------------------------------------------
// Launch: 5 kernels.
// ---------------------------------------------------------------------------
extern "C" void kernel_launch(void* const* d_in, const int* in_sizes, int n_in,
                              void* d_out, int out_size, void* d_ws, size_t ws_size,
                              hipStream_t stream) {
  const float* hs = (const float*)d_in[0];  // [4096, 1024]
  const float* Wq = (const float*)d_in[1];  // [1024, 256]
  const float* Wk = (const float*)d_in[2];  // [1024, 256]
  const float* Wv = (const float*)d_in[3];  // [1024, 1024]
  const float* Wo = (const float*)d_in[4];  // [1024, 1024]
  float* out = (float*)d_out;               // [4096, 1024]

  char* ws = (char*)d_ws;
  _Float16* WqkvT = (_Float16*)ws;                    // [1536][1024] = 3 MiB
  _Float16* WoT   = (_Float16*)(ws + (3ull << 20));   // [1024][1024] = 2 MiB
  _Float16* HS16  = (_Float16*)(ws + (5ull << 20));   // [4096][1024] = 8 MiB
  _Float16* QKV   = (_Float16*)(ws + (13ull << 20));  // [4096][1536] = 12 MiB
  _Float16* Oatt  = (_Float16*)(ws + (25ull << 20));  // [4096][1024] = 8 MiB
  float*    QKVe  = (float*)(ws + (33ull << 20));     // [8][1536] fp32

  const int M = BB * LL;  // 4096

  // prep: W transposes + fp32 early-QKV + hs fp32->fp16 cast (one launch)
  prep<<<dim3(3632), 256, 0, stream>>>(Wq, Wk, Wv, Wo, hs, WqkvT, WoT, QKVe, HS16);

  // fused QKV projection: 128x64 tiles (round-16 verified optimum)
  gemm_f16<_Float16><<<dim3(RQKV / 64, M / 128), 256, 0, stream>>>(
      HS16, WqkvT, QKV, M, RQKV, DD);

  // attention: grid (bh, pair) — bh-major for XCD L2 locality
  attn_mfma4<<<dim3(BB * HH, LL / 128), 256, 0, stream>>>(QKV, Oatt);

  // fp32-exact first-NFIX rows per (b,h)
  fix_final<<<dim3(BB * HH), 256, 0, stream>>>(QKVe, Oatt);

  // output projection: 128x64 tiles
  gemm_f16<float><<<dim3(DD / 64, M / 128), 256, 0, stream>>>(
      Oatt, WoT, out, M, DD, DD);
}